// Round 1
// baseline (2477.172 us; speedup 1.0000x reference)
//
#include <hip/hip_runtime.h>
#include <math.h>

#define FIN 767
#define HD 16
#define NC 10

__device__ __forceinline__ unsigned fmapk(float f){
    unsigned u = __float_as_uint(f);
    return (u & 0x80000000u) ? ~u : (u | 0x80000000u);
}
__device__ __forceinline__ float funmapk(unsigned k){
    return (k & 0x80000000u) ? __uint_as_float(k ^ 0x80000000u) : __uint_as_float(~k);
}

// init: zero x1 (in d_out), amax keys, denom; build wT[768][16] from lin1_w[16][767]
__global__ void k_init(float* __restrict__ x1, unsigned* __restrict__ amax,
                       float* __restrict__ denom, const float* __restrict__ w1,
                       float* __restrict__ wt, int N){
    int t = blockIdx.x * 256 + threadIdx.x;
    if (t < 4*N){
        ((float4*)x1)[t] = make_float4(0.f,0.f,0.f,0.f);
    }
    if (t < N){ amax[t] = 0u; denom[t] = 0.f; }
    if (t < 768*16){
        int c = t >> 4, h = t & 15;
        wt[t] = (c < FIN) ? w1[h*FIN + c] : 0.f;
    }
}

// h = relu(x @ W1^T + b1); hn = h / max(||h||,eps)
// block = 256 thr (4 waves) owns 64 rows. x staged in LDS [64][97] (pad kills conflicts),
// W read as wave-uniform scalar float4 loads from wT. lane == row -> no per-dot reduction.
__global__ __launch_bounds__(256) void k_gemm1(const float* __restrict__ x,
        const float* __restrict__ wt, const float* __restrict__ bias,
        float* __restrict__ h_out, float* __restrict__ hn_out, int N){
    __shared__ float smem[2*6208]; // 2 x [64][97] floats = 49664 B ; reduction aliases first half
    const int t  = threadIdx.x;
    const int wv = t >> 6;
    const int ln = t & 63;
    const int row0 = blockIdx.x * 64;

    float acc[16];
    #pragma unroll
    for (int i=0;i<16;i++) acc[i]=0.f;

    float stg[24];

    auto load_chunk = [&](int k){
        #pragma unroll
        for (int i=0;i<24;i++){
            int f = i*256 + t;
            int r = f / 96, c = f - r*96;
            int col = k*96 + c;
            int row = row0 + r;
            stg[i] = (col < FIN && row < N) ? x[(size_t)row*FIN + col] : 0.f;
        }
    };
    auto write_chunk = [&](float* buf){
        #pragma unroll
        for (int i=0;i<24;i++){
            int f = i*256 + t;
            int r = f / 96, c = f - r*96;
            buf[r*97 + c] = stg[i];
        }
    };

    load_chunk(0);
    for (int k=0;k<8;k++){
        float* buf = (k&1) ? (smem + 6208) : smem;
        write_chunk(buf);
        if (k < 7) load_chunk(k+1);
        __syncthreads();
        const int cbase = k*96 + wv*24;
        const float* brow = buf + ln*97 + wv*24;
        #pragma unroll
        for (int j=0;j<24;j++){
            int c = cbase + j;
            if (c < FIN){
                float xv = brow[j];
                int cu = __builtin_amdgcn_readfirstlane(c);
                const float4* wtc = (const float4*)(wt + cu*16);
                float4 w0 = wtc[0], w1 = wtc[1], w2 = wtc[2], w3 = wtc[3];
                acc[0]  += xv*w0.x; acc[1]  += xv*w0.y; acc[2]  += xv*w0.z; acc[3]  += xv*w0.w;
                acc[4]  += xv*w1.x; acc[5]  += xv*w1.y; acc[6]  += xv*w1.z; acc[7]  += xv*w1.w;
                acc[8]  += xv*w2.x; acc[9]  += xv*w2.y; acc[10] += xv*w2.z; acc[11] += xv*w2.w;
                acc[12] += xv*w3.x; acc[13] += xv*w3.y; acc[14] += xv*w3.z; acc[15] += xv*w3.w;
            }
        }
        __syncthreads();
    }

    // cross-wave reduce via LDS: red[4][64][20] (aliases smem[0..5120), last compute read smem+6208)
    float* red = smem;
    #pragma unroll
    for (int hq=0; hq<4; hq++){
        float4 v = make_float4(acc[hq*4+0], acc[hq*4+1], acc[hq*4+2], acc[hq*4+3]);
        *(float4*)&red[(wv*64 + ln)*20 + hq*4] = v;
    }
    __syncthreads();
    int row = t >> 2, hq2 = t & 3;
    float4 s = make_float4(0.f,0.f,0.f,0.f);
    #pragma unroll
    for (int w=0; w<4; w++){
        float4 p = *(const float4*)&red[(w*64 + row)*20 + hq2*4];
        s.x += p.x; s.y += p.y; s.z += p.z; s.w += p.w;
    }
    float4 b4 = *((const float4*)bias + hq2);
    s.x = fmaxf(s.x + b4.x, 0.f);
    s.y = fmaxf(s.y + b4.y, 0.f);
    s.z = fmaxf(s.z + b4.z, 0.f);
    s.w = fmaxf(s.w + b4.w, 0.f);
    float ss = s.x*s.x + s.y*s.y + s.z*s.z + s.w*s.w;
    ss += __shfl_xor(ss, 1);
    ss += __shfl_xor(ss, 2);
    float inv = 1.f / fmaxf(sqrtf(ss), 1e-12f);
    int grow = row0 + row;
    if (grow < N){
        *(float4*)&h_out[(size_t)grow*16 + hq2*4] = s;
        float4 sn = make_float4(s.x*inv, s.y*inv, s.z*inv, s.w*inv);
        *(float4*)&hn_out[(size_t)grow*16 + hq2*4] = sn;
    }
}

// alpha[e] = beta * dot(gn[src], gn[dst]); atomicMax amax[dst]. 4 lanes per edge.
__global__ __launch_bounds__(256) void k_alpha(const int* __restrict__ ei,
        const float* __restrict__ gn, float* __restrict__ alphab,
        unsigned* __restrict__ amax, const float* __restrict__ beta_p, int E, int NP){
    int t = blockIdx.x*256 + threadIdx.x;
    int e = t >> 2, q = t & 3;
    if (e >= NP) return;
    int s, d;
    if (e < E){ s = ei[e]; d = ei[E + e]; } else { s = d = e - E; }
    const float4* g4 = (const float4*)gn;
    float4 a = g4[(size_t)s*4 + q], b = g4[(size_t)d*4 + q];
    float p = a.x*b.x + a.y*b.y + a.z*b.z + a.w*b.w;
    p += __shfl_xor(p, 1);
    p += __shfl_xor(p, 2);
    if (q == 0){
        float beta = beta_p ? beta_p[0] : 1.0f;
        float al = beta * p;
        alphab[e] = al;
        atomicMax(&amax[d], fmapk(al));
    }
}

// ex = exp(alpha - amax[dst]) stored back; denom[dst] += ex
__global__ __launch_bounds__(256) void k_exp(const int* __restrict__ ei,
        float* __restrict__ alphab, const unsigned* __restrict__ amax,
        float* __restrict__ denom, int E, int NP){
    int e = blockIdx.x*256 + threadIdx.x;
    if (e >= NP) return;
    int d = (e < E) ? ei[E + e] : e - E;
    float a = alphab[e];
    float m = funmapk(amax[d]);
    float ex = expf(a - m);
    alphab[e] = ex;
    atomicAdd(&denom[d], ex);
}

// out[dst] += (ex/denom[dst]) * g[src]; 4 lanes per edge, 4 atomics each
__global__ __launch_bounds__(256) void k_aggr(const int* __restrict__ ei,
        const float* __restrict__ alphab, const float* __restrict__ denom,
        const float* __restrict__ g, float* __restrict__ out, int E, int NP){
    int t = blockIdx.x*256 + threadIdx.x;
    int e = t >> 2, q = t & 3;
    if (e >= NP) return;
    int s, d;
    if (e < E){ s = ei[e]; d = ei[E + e]; } else { s = d = e - E; }
    float w = alphab[e] / denom[d];
    float4 gv = ((const float4*)g)[(size_t)s*4 + q];
    float* o = out + (size_t)d*16 + q*4;
    atomicAdd(o+0, w*gv.x);
    atomicAdd(o+1, w*gv.y);
    atomicAdd(o+2, w*gv.z);
    atomicAdd(o+3, w*gv.w);
}

// normalize x1 -> x1n; re-init amax/denom; zero x2
__global__ __launch_bounds__(256) void k_norm2(const float* __restrict__ xin,
        float* __restrict__ xn, unsigned* __restrict__ amax, float* __restrict__ denom,
        float* __restrict__ zbuf, int N){
    int t = blockIdx.x*256 + threadIdx.x;
    int row = t >> 2, hq = t & 3;
    if (row >= N) return;
    float4 v = ((const float4*)xin)[(size_t)row*4 + hq];
    float ss = v.x*v.x + v.y*v.y + v.z*v.z + v.w*v.w;
    ss += __shfl_xor(ss, 1);
    ss += __shfl_xor(ss, 2);
    float inv = 1.f / fmaxf(sqrtf(ss), 1e-12f);
    ((float4*)xn)[(size_t)row*4 + hq] = make_float4(v.x*inv, v.y*inv, v.z*inv, v.w*inv);
    ((float4*)zbuf)[(size_t)row*4 + hq] = make_float4(0.f,0.f,0.f,0.f);
    if (hq == 0){ amax[row] = 0u; denom[row] = 0.f; }
}

// logits = x2 @ W2^T + b2 ; log_softmax rows of 10
__global__ __launch_bounds__(256) void k_logits(const float* __restrict__ x2,
        const float* __restrict__ w2, const float* __restrict__ b2,
        float* __restrict__ out, int N){
    int r = blockIdx.x*256 + threadIdx.x;
    if (r >= N) return;
    float xv[16];
    #pragma unroll
    for (int i=0;i<4;i++){
        float4 v = ((const float4*)x2)[(size_t)r*4 + i];
        xv[i*4+0]=v.x; xv[i*4+1]=v.y; xv[i*4+2]=v.z; xv[i*4+3]=v.w;
    }
    float lg[NC];
    #pragma unroll
    for (int c=0;c<NC;c++){
        float sum = b2[c];
        #pragma unroll
        for (int k=0;k<16;k++) sum += xv[k]*w2[c*16+k];
        lg[c] = sum;
    }
    float m = lg[0];
    #pragma unroll
    for (int c=1;c<NC;c++) m = fmaxf(m, lg[c]);
    float se = 0.f;
    #pragma unroll
    for (int c=0;c<NC;c++) se += expf(lg[c]-m);
    float lse = m + logf(se);
    #pragma unroll
    for (int c=0;c<NC;c++) out[(size_t)r*NC + c] = lg[c] - lse;
}

extern "C" void kernel_launch(void* const* d_in, const int* in_sizes, int n_in,
                              void* d_out, int out_size, void* d_ws, size_t ws_size,
                              hipStream_t stream){
    const float* x     = (const float*)d_in[0];
    const int*   ei    = (const int*)d_in[1];
    const float* w1    = (const float*)d_in[2];
    const float* b1    = (const float*)d_in[3];
    const float* beta2 = (const float*)d_in[4];
    const float* w2    = (const float*)d_in[5];
    const float* b2    = (const float*)d_in[6];
    float* out = (float*)d_out;

    const int N  = in_sizes[0] / FIN;
    const int E  = in_sizes[1] / 2;
    const int NP = E + N;

    float* ws   = (float*)d_ws;
    float* h    = ws;                       // N*16   (reused as x2 later)
    float* hn   = h   + (size_t)N*16;       // N*16
    float* x1n  = hn  + (size_t)N*16;       // N*16
    unsigned* amax = (unsigned*)(x1n + (size_t)N*16);  // N
    float* denom  = (float*)(amax + N);     // N
    float* alphab = denom + N;              // NP
    float* wt     = alphab + NP;            // 768*16
    float* x2     = h;                      // alias: h dead after aggr1
    float* x1     = out + (size_t)N*NC;     // second output region

    int egrid4 = (NP*4 + 255)/256;
    int egrid  = (NP + 255)/256;

    k_init  <<<(4*N + 255)/256, 256, 0, stream>>>(x1, amax, denom, w1, wt, N);
    k_gemm1 <<<(N + 63)/64,     256, 0, stream>>>(x, wt, b1, h, hn, N);
    // prop1 (beta = 1)
    k_alpha <<<egrid4, 256, 0, stream>>>(ei, hn, alphab, amax, nullptr, E, NP);
    k_exp   <<<egrid,  256, 0, stream>>>(ei, alphab, amax, denom, E, NP);
    k_aggr  <<<egrid4, 256, 0, stream>>>(ei, alphab, denom, h, x1, E, NP);
    // renorm + reinit + zero x2
    k_norm2 <<<(4*N + 255)/256, 256, 0, stream>>>(x1, x1n, amax, denom, x2, N);
    // prop2 (beta = beta2[0])
    k_alpha <<<egrid4, 256, 0, stream>>>(ei, x1n, alphab, amax, beta2, E, NP);
    k_exp   <<<egrid,  256, 0, stream>>>(ei, alphab, amax, denom, E, NP);
    k_aggr  <<<egrid4, 256, 0, stream>>>(ei, alphab, denom, x1, x2, E, NP);
    // output head
    k_logits<<<(N + 255)/256,   256, 0, stream>>>(x2, w2, b2, out, N);
}

// Round 2
// 1409.398 us; speedup vs baseline: 1.7576x; 1.7576x over previous
//
#include <hip/hip_runtime.h>
#include <math.h>

#define FIN 767
#define HD 16
#define NC 10

// ---------- setup: zero degree counters, build wT[768][16] ----------
__global__ __launch_bounds__(256) void k_setup(int* __restrict__ deg,
        const float* __restrict__ w1, float* __restrict__ wt, int N){
    int t = blockIdx.x*256 + threadIdx.x;
    if (t < N) deg[t] = 0;
    if (t < 768*16){
        int c = t >> 4, h = t & 15;
        wt[t] = (c < FIN) ? w1[h*FIN + c] : 0.f;
    }
}

// ---------- CSR build ----------
__global__ __launch_bounds__(256) void k_degree(const int* __restrict__ ei,
        int* __restrict__ deg, int E){
    int e = blockIdx.x*256 + threadIdx.x;
    if (e < E) atomicAdd(&deg[ei[E + e]], 1);
}

// single block of 1024: exclusive scan deg -> rowptr[0..N] + cursor copy
__global__ __launch_bounds__(1024) void k_scan(const int* __restrict__ deg,
        int* __restrict__ rowptr, int* __restrict__ cursor, int N){
    __shared__ int sh[1024];
    int tid = threadIdx.x;
    int c = (N + 1023) >> 10;
    int beg = tid*c, end = min(beg + c, N);
    int sum = 0;
    for (int i=beg; i<end; ++i) sum += deg[i];
    sh[tid] = sum; __syncthreads();
    for (int off=1; off<1024; off<<=1){
        int v = (tid >= off) ? sh[tid-off] : 0;
        __syncthreads();
        sh[tid] += v;
        __syncthreads();
    }
    int run = sh[tid] - sum;           // exclusive prefix
    for (int i=beg; i<end; ++i){
        rowptr[i] = run; cursor[i] = run; run += deg[i];
    }
    if (tid == 1023) rowptr[N] = sh[1023];
}

__global__ __launch_bounds__(256) void k_scatter(const int* __restrict__ ei,
        int* __restrict__ cursor, int* __restrict__ csr, int E){
    int e = blockIdx.x*256 + threadIdx.x;
    if (e >= E) return;
    int s = ei[e], d = ei[E + e];
    int pos = atomicAdd(&cursor[d], 1);
    csr[pos] = s;
}

// ---------- h = relu(x @ W1^T + b1); invn = 1/max(||h||,eps) ----------
// block = 256 thr (4 waves) owns 64 rows. x staged in LDS [64][97] double-buffered.
__global__ __launch_bounds__(256) void k_gemm1(const float* __restrict__ x,
        const float* __restrict__ wt, const float* __restrict__ bias,
        float* __restrict__ h_out, float* __restrict__ invn_out, int N){
    __shared__ float smem[2*6208];
    const int t  = threadIdx.x;
    const int wv = t >> 6;
    const int ln = t & 63;
    const int row0 = blockIdx.x * 64;

    float acc[16];
    #pragma unroll
    for (int i=0;i<16;i++) acc[i]=0.f;

    float stg[24];
    auto load_chunk = [&](int k){
        #pragma unroll
        for (int i=0;i<24;i++){
            int f = i*256 + t;
            int r = f / 96, c = f - r*96;
            int col = k*96 + c;
            int row = row0 + r;
            stg[i] = (col < FIN && row < N) ? x[(size_t)row*FIN + col] : 0.f;
        }
    };
    auto write_chunk = [&](float* buf){
        #pragma unroll
        for (int i=0;i<24;i++){
            int f = i*256 + t;
            int r = f / 96, c = f - r*96;
            buf[r*97 + c] = stg[i];
        }
    };

    load_chunk(0);
    for (int k=0;k<8;k++){
        float* buf = (k&1) ? (smem + 6208) : smem;
        write_chunk(buf);
        if (k < 7) load_chunk(k+1);
        __syncthreads();
        const int cbase = k*96 + wv*24;
        const float* brow = buf + ln*97 + wv*24;
        #pragma unroll
        for (int j=0;j<24;j++){
            int c = cbase + j;
            if (c < FIN){
                float xv = brow[j];
                int cu = __builtin_amdgcn_readfirstlane(c);
                const float4* wtc = (const float4*)(wt + cu*16);
                float4 w0 = wtc[0], w1 = wtc[1], w2 = wtc[2], w3 = wtc[3];
                acc[0]  += xv*w0.x; acc[1]  += xv*w0.y; acc[2]  += xv*w0.z; acc[3]  += xv*w0.w;
                acc[4]  += xv*w1.x; acc[5]  += xv*w1.y; acc[6]  += xv*w1.z; acc[7]  += xv*w1.w;
                acc[8]  += xv*w2.x; acc[9]  += xv*w2.y; acc[10] += xv*w2.z; acc[11] += xv*w2.w;
                acc[12] += xv*w3.x; acc[13] += xv*w3.y; acc[14] += xv*w3.z; acc[15] += xv*w3.w;
            }
        }
        __syncthreads();
    }

    float* red = smem;
    #pragma unroll
    for (int hq=0; hq<4; hq++){
        float4 v = make_float4(acc[hq*4+0], acc[hq*4+1], acc[hq*4+2], acc[hq*4+3]);
        *(float4*)&red[(wv*64 + ln)*20 + hq*4] = v;
    }
    __syncthreads();
    int row = t >> 2, hq2 = t & 3;
    float4 s = make_float4(0.f,0.f,0.f,0.f);
    #pragma unroll
    for (int w=0; w<4; w++){
        float4 p = *(const float4*)&red[(w*64 + row)*20 + hq2*4];
        s.x += p.x; s.y += p.y; s.z += p.z; s.w += p.w;
    }
    float4 b4 = *((const float4*)bias + hq2);
    s.x = fmaxf(s.x + b4.x, 0.f);
    s.y = fmaxf(s.y + b4.y, 0.f);
    s.z = fmaxf(s.z + b4.z, 0.f);
    s.w = fmaxf(s.w + b4.w, 0.f);
    float ss = s.x*s.x + s.y*s.y + s.z*s.z + s.w*s.w;
    ss += __shfl_xor(ss, 1);
    ss += __shfl_xor(ss, 2);
    float inv = 1.f / fmaxf(sqrtf(ss), 1e-12f);
    int grow = row0 + row;
    if (grow < N){
        *(float4*)&h_out[(size_t)grow*16 + hq2*4] = s;
        if (hq2 == 0) invn_out[grow] = inv;
    }
}

// ---------- fused AGNN propagation: online segment-softmax + aggregation ----------
// 16 lanes per node (lane = feature dim), 4 nodes per wave, zero atomics.
// cos(x_s,x_d) = (x_s . x_d) * invn_s * invn_d ; self-loop handled analytically.
__global__ __launch_bounds__(256) void k_prop(const int* __restrict__ rowptr,
        const int* __restrict__ csr, const float* __restrict__ xf,
        const float* __restrict__ invn, const float* __restrict__ beta_p,
        float* __restrict__ outf, float* __restrict__ invn_out, int N){
    int t = blockIdx.x*256 + threadIdx.x;
    int node = t >> 4, ln = t & 15;
    if (node >= N) return;
    float beta = beta_p ? beta_p[0] : 1.0f;

    float xd  = xf[(size_t)node*16 + ln];
    float ivd = invn[node];
    int beg = rowptr[node], end = rowptr[node+1];

    // self-loop first: alpha = beta * (xd.xd) * ivd^2 ; exp(0)=1 after max
    float p = xd*xd;
    p += __shfl_xor(p,1); p += __shfl_xor(p,2); p += __shfl_xor(p,4); p += __shfl_xor(p,8);
    float m = beta * p * ivd * ivd;
    float s = 1.f;
    float acc = xd;

    for (int j = beg; j < end; ++j){
        int sidx = csr[j];
        float xs  = xf[(size_t)sidx*16 + ln];
        float ivs = invn[sidx];
        float q = xs*xd;
        q += __shfl_xor(q,1); q += __shfl_xor(q,2); q += __shfl_xor(q,4); q += __shfl_xor(q,8);
        float alpha = beta * q * ivd * ivs;
        float nm = fmaxf(m, alpha);
        float sc = __expf(m - nm);
        float pe = __expf(alpha - nm);
        s   = s*sc + pe;
        acc = acc*sc + pe*xs;
        m = nm;
    }

    float o = acc / s;
    outf[(size_t)node*16 + ln] = o;

    float ss = o*o;
    ss += __shfl_xor(ss,1); ss += __shfl_xor(ss,2); ss += __shfl_xor(ss,4); ss += __shfl_xor(ss,8);
    if (ln == 0 && invn_out) invn_out[node] = 1.f / fmaxf(sqrtf(ss), 1e-12f);
}

// ---------- logits = x2 @ W2^T + b2 ; log_softmax ----------
__global__ __launch_bounds__(256) void k_logits(const float* __restrict__ x2,
        const float* __restrict__ w2, const float* __restrict__ b2,
        float* __restrict__ out, int N){
    int r = blockIdx.x*256 + threadIdx.x;
    if (r >= N) return;
    float xv[16];
    #pragma unroll
    for (int i=0;i<4;i++){
        float4 v = ((const float4*)x2)[(size_t)r*4 + i];
        xv[i*4+0]=v.x; xv[i*4+1]=v.y; xv[i*4+2]=v.z; xv[i*4+3]=v.w;
    }
    float lg[NC];
    #pragma unroll
    for (int c=0;c<NC;c++){
        float sum = b2[c];
        #pragma unroll
        for (int k=0;k<16;k++) sum += xv[k]*w2[c*16+k];
        lg[c] = sum;
    }
    float mx = lg[0];
    #pragma unroll
    for (int c=1;c<NC;c++) mx = fmaxf(mx, lg[c]);
    float se = 0.f;
    #pragma unroll
    for (int c=0;c<NC;c++) se += __expf(lg[c]-mx);
    float lse = mx + __logf(se);
    #pragma unroll
    for (int c=0;c<NC;c++) out[(size_t)r*NC + c] = lg[c] - lse;
}

extern "C" void kernel_launch(void* const* d_in, const int* in_sizes, int n_in,
                              void* d_out, int out_size, void* d_ws, size_t ws_size,
                              hipStream_t stream){
    const float* x     = (const float*)d_in[0];
    const int*   ei    = (const int*)d_in[1];
    const float* w1    = (const float*)d_in[2];
    const float* b1    = (const float*)d_in[3];
    const float* beta2 = (const float*)d_in[4];
    const float* w2    = (const float*)d_in[5];
    const float* b2    = (const float*)d_in[6];
    float* out = (float*)d_out;

    const int N = in_sizes[0] / FIN;
    const int E = in_sizes[1] / 2;

    // workspace layout
    float* ws    = (float*)d_ws;
    float* wt    = ws;                       // 12288
    float* h     = wt   + 12288;             // N*16
    float* x2    = h    + (size_t)N*16;      // N*16
    float* invn0 = x2   + (size_t)N*16;      // N
    float* invn1 = invn0 + N;                // N
    float* invn2 = invn1 + N;                // N
    int*   deg    = (int*)(invn2 + N);       // N
    int*   rowptr = deg + N;                 // N+1
    int*   cursor = rowptr + (N+1);          // N
    int*   csr    = cursor + N;              // E

    float* x1 = out + (size_t)N*NC;          // second output region

    int egrid = (E + 255)/256;

    k_setup  <<<(N + 255)/256, 256, 0, stream>>>(deg, w1, wt, N);
    k_degree <<<egrid, 256, 0, stream>>>(ei, deg, E);
    k_scan   <<<1, 1024, 0, stream>>>(deg, rowptr, cursor, N);
    k_scatter<<<egrid, 256, 0, stream>>>(ei, cursor, csr, E);

    k_gemm1  <<<(N + 63)/64, 256, 0, stream>>>(x, wt, b1, h, invn0, N);

    k_prop   <<<(N*16 + 255)/256, 256, 0, stream>>>(rowptr, csr, h,  invn0, nullptr, x1, invn1, N);
    k_prop   <<<(N*16 + 255)/256, 256, 0, stream>>>(rowptr, csr, x1, invn1, beta2,   x2, invn2, N);

    k_logits <<<(N + 255)/256, 256, 0, stream>>>(x2, w2, b2, out, N);
}